// Round 1
// baseline (293.422 us; speedup 1.0000x reference)
//
#include <hip/hip_runtime.h>

typedef __bf16 bf16x8 __attribute__((ext_vector_type(8)));
typedef float  f32x4  __attribute__((ext_vector_type(4)));

#define N_HEAD 12
#define HEAD   64
#define HID    768
#define SEQ    2048
#define BATCH  2
#define MROWS  (BATCH*SEQ)   // 4096

// ---------------- cast x (fp32 -> bf16), 8 elems/thread ----------------
__global__ __launch_bounds__(256) void cast_f32_bf16(const float* __restrict__ in,
                                                     __bf16* __restrict__ out, int n8) {
    int i = blockIdx.x * 256 + threadIdx.x;
    if (i >= n8) return;
    const float4* p = (const float4*)in;
    float4 a = p[2*i], b = p[2*i+1];
    bf16x8 o;
    o[0]=(__bf16)a.x; o[1]=(__bf16)a.y; o[2]=(__bf16)a.z; o[3]=(__bf16)a.w;
    o[4]=(__bf16)b.x; o[5]=(__bf16)b.y; o[6]=(__bf16)b.z; o[7]=(__bf16)b.w;
    *(bf16x8*)&out[(size_t)8*i] = o;
}

// ------------- transpose + cast: in[R][C] fp32 -> out[C][R] bf16 -------------
__global__ __launch_bounds__(256) void transpose_cast(const float* __restrict__ in,
                                                      __bf16* __restrict__ out, int R, int C) {
    __shared__ float t[32][33];
    int bx = blockIdx.x * 32;  // C dim
    int by = blockIdx.y * 32;  // R dim
    int x = threadIdx.x, y = threadIdx.y;  // (32, 8)
    #pragma unroll
    for (int i = 0; i < 32; i += 8) t[y+i][x] = in[(size_t)(by+y+i)*C + bx + x];
    __syncthreads();
    #pragma unroll
    for (int i = 0; i < 32; i += 8) out[(size_t)(bx+y+i)*R + by + x] = (__bf16)t[x][y+i];
}

// ---------------- MFMA GEMM, A[M][K] bf16, Bt[N][K] bf16 ----------------
// EPI 0: Cout[row][col] = acc + bias[col]  (fp32)
// EPI 1: qkv scatter: col<768 -> Q[bh][s][d], <1536 -> K[bh][s][d], else V^T[bh][d][s]
template<int EPI>
__global__ __launch_bounds__(256) void gemm_bt(
    const __bf16* __restrict__ A, const __bf16* __restrict__ Bt,
    const float* __restrict__ bias, float* __restrict__ Cout,
    __bf16* __restrict__ Qo, __bf16* __restrict__ Ko, __bf16* __restrict__ Vo,
    int M, int N, int K)
{
    __shared__ __bf16 As[128][40];
    __shared__ __bf16 Bs[128][40];
    int tid = threadIdx.x;
    int m0 = blockIdx.y * 128, n0 = blockIdx.x * 128;
    int wave = tid >> 6, lane = tid & 63, lr = lane & 15, lk = lane >> 4;
    int wr = wave >> 1, wc = wave & 1;

    f32x4 acc[4][4];
    f32x4 zz = {0.f, 0.f, 0.f, 0.f};
    #pragma unroll
    for (int m = 0; m < 4; m++)
        #pragma unroll
        for (int n = 0; n < 4; n++) acc[m][n] = zz;

    for (int k0 = 0; k0 < K; k0 += 32) {
        #pragma unroll
        for (int i = 0; i < 2; i++) {
            int u = tid + 256*i;           // 0..511 16B-units
            int row = u >> 2, cu = u & 3;
            *(bf16x8*)&As[row][cu*8] = *(const bf16x8*)&A [(size_t)(m0+row)*K + k0 + cu*8];
            *(bf16x8*)&Bs[row][cu*8] = *(const bf16x8*)&Bt[(size_t)(n0+row)*K + k0 + cu*8];
        }
        __syncthreads();
        bf16x8 af[4], bfr[4];
        #pragma unroll
        for (int m = 0; m < 4; m++) af[m]  = *(const bf16x8*)&As[wr*64 + m*16 + lr][lk*8];
        #pragma unroll
        for (int n = 0; n < 4; n++) bfr[n] = *(const bf16x8*)&Bs[wc*64 + n*16 + lr][lk*8];
        #pragma unroll
        for (int m = 0; m < 4; m++)
            #pragma unroll
            for (int n = 0; n < 4; n++)
                acc[m][n] = __builtin_amdgcn_mfma_f32_16x16x32_bf16(af[m], bfr[n], acc[m][n], 0, 0, 0);
        __syncthreads();
    }

    #pragma unroll
    for (int m = 0; m < 4; m++)
    #pragma unroll
    for (int n = 0; n < 4; n++)
    #pragma unroll
    for (int r = 0; r < 4; r++) {
        int row = m0 + wr*64 + m*16 + lk*4 + r;   // C/D layout (m89-verified)
        int col = n0 + wc*64 + n*16 + lr;
        float v = acc[m][n][r] + bias[col];
        if (EPI == 0) {
            Cout[(size_t)row * N + col] = v;
        } else {
            int b_idx = row >> 11, s = row & 2047;
            int which = col / HID, hc = col % HID;
            int bh = b_idx * N_HEAD + (hc >> 6);
            int d = hc & 63;
            __bf16 bv = (__bf16)v;
            if (which == 0)      Qo[((size_t)bh*SEQ + s)*HEAD + d] = bv;
            else if (which == 1) Ko[((size_t)bh*SEQ + s)*HEAD + d] = bv;
            else                 Vo[((size_t)bh*HEAD + d)*SEQ + s] = bv;
        }
    }
}

// ---------------- causal flash attention ----------------
// grid (SEQ/128, BATCH*N_HEAD), block 256. Wave w owns 32 q-rows.
__global__ __launch_bounds__(256) void flash_attn(
    const __bf16* __restrict__ Q, const __bf16* __restrict__ Km,
    const __bf16* __restrict__ Vt, __bf16* __restrict__ ctx)
{
    __shared__ __bf16 P[4][32*64];
    int tid = threadIdx.x, wave = tid >> 6, lane = tid & 63, lr = lane & 15, lk = lane >> 4;
    int bh = blockIdx.y, b_idx = bh / N_HEAD, h = bh % N_HEAD;
    int q0 = blockIdx.x * 128 + wave * 32;
    char* pb = (char*)&P[wave][0];
    const size_t hb = (size_t)bh * SEQ * HEAD;

    bf16x8 qf[2][2];
    #pragma unroll
    for (int rb = 0; rb < 2; rb++)
        #pragma unroll
        for (int kb = 0; kb < 2; kb++)
            qf[rb][kb] = *(const bf16x8*)&Q[hb + (size_t)(q0 + rb*16 + lr)*HEAD + kb*32 + lk*8];

    f32x4 acc[2][4];
    float msta[2][4], lsum[2][4];
    f32x4 zz = {0.f, 0.f, 0.f, 0.f};
    #pragma unroll
    for (int rb = 0; rb < 2; rb++)
        #pragma unroll
        for (int r = 0; r < 4; r++) { msta[rb][r] = -1e30f; lsum[rb][r] = 0.f; }
    #pragma unroll
    for (int rb = 0; rb < 2; rb++)
        #pragma unroll
        for (int db = 0; db < 4; db++) acc[rb][db] = zz;

    int nt = ((q0 + 31) >> 6) + 1;
    for (int t = 0; t < nt; t++) {
        int kv0 = t * 64;
        bf16x8 kf[4][2];
        #pragma unroll
        for (int cb = 0; cb < 4; cb++)
            #pragma unroll
            for (int kb = 0; kb < 2; kb++)
                kf[cb][kb] = *(const bf16x8*)&Km[hb + (size_t)(kv0 + cb*16 + lr)*HEAD + kb*32 + lk*8];

        f32x4 sc[2][4];
        #pragma unroll
        for (int rb = 0; rb < 2; rb++)
            #pragma unroll
            for (int cb = 0; cb < 4; cb++) {
                f32x4 z = zz;
                z = __builtin_amdgcn_mfma_f32_16x16x32_bf16(qf[rb][0], kf[cb][0], z, 0, 0, 0);
                sc[rb][cb] = __builtin_amdgcn_mfma_f32_16x16x32_bf16(qf[rb][1], kf[cb][1], z, 0, 0, 0);
            }

        // scale + causal mask
        #pragma unroll
        for (int rb = 0; rb < 2; rb++)
        #pragma unroll
        for (int cb = 0; cb < 4; cb++)
        #pragma unroll
        for (int r = 0; r < 4; r++) {
            int qg = q0 + rb*16 + lk*4 + r;
            int kg = kv0 + cb*16 + lr;
            float v = sc[rb][cb][r] * 0.125f;
            sc[rb][cb][r] = (kg <= qg) ? v : -1e30f;
        }

        // online softmax (row lives in a 16-lane group; reduce over lr)
        #pragma unroll
        for (int rb = 0; rb < 2; rb++)
        #pragma unroll
        for (int r = 0; r < 4; r++) {
            float pm = fmaxf(fmaxf(sc[rb][0][r], sc[rb][1][r]), fmaxf(sc[rb][2][r], sc[rb][3][r]));
            #pragma unroll
            for (int off = 1; off < 16; off <<= 1) pm = fmaxf(pm, __shfl_xor(pm, off, 16));
            float mn = fmaxf(msta[rb][r], pm);
            float al = __expf(msta[rb][r] - mn);
            float rs = 0.f;
            #pragma unroll
            for (int cb = 0; cb < 4; cb++) {
                float p = __expf(sc[rb][cb][r] - mn);
                sc[rb][cb][r] = p;
                rs += p;
            }
            #pragma unroll
            for (int off = 1; off < 16; off <<= 1) rs += __shfl_xor(rs, off, 16);
            lsum[rb][r] = lsum[rb][r] * al + rs;
            msta[rb][r] = mn;
            #pragma unroll
            for (int db = 0; db < 4; db++) acc[rb][db][r] *= al;
        }

        // write P (C-layout) into XOR-swizzled LDS
        #pragma unroll
        for (int rb = 0; rb < 2; rb++)
        #pragma unroll
        for (int cb = 0; cb < 4; cb++)
        #pragma unroll
        for (int r = 0; r < 4; r++) {
            int prow = rb*16 + lk*4 + r;
            int off = prow*128 + (cb*16 + lr)*2;
            off ^= (prow & 7) << 4;
            *(__bf16*)(pb + off) = (__bf16)sc[rb][cb][r];
        }
        asm volatile("s_waitcnt lgkmcnt(0)" ::: "memory");

        bf16x8 vf[4][2];
        #pragma unroll
        for (int db = 0; db < 4; db++)
            #pragma unroll
            for (int ks = 0; ks < 2; ks++)
                vf[db][ks] = *(const bf16x8*)&Vt[(size_t)(bh*HEAD + db*16 + lr)*SEQ + kv0 + ks*32 + lk*8];

        #pragma unroll
        for (int rb = 0; rb < 2; rb++) {
            bf16x8 pa[2];
            #pragma unroll
            for (int ks = 0; ks < 2; ks++) {
                int prow = rb*16 + lr;
                int off = prow*128 + ks*64 + lk*16;
                off ^= (prow & 7) << 4;
                pa[ks] = *(const bf16x8*)(pb + off);
            }
            #pragma unroll
            for (int db = 0; db < 4; db++) {
                acc[rb][db] = __builtin_amdgcn_mfma_f32_16x16x32_bf16(pa[0], vf[db][0], acc[rb][db], 0, 0, 0);
                acc[rb][db] = __builtin_amdgcn_mfma_f32_16x16x32_bf16(pa[1], vf[db][1], acc[rb][db], 0, 0, 0);
            }
        }
    }

    #pragma unroll
    for (int rb = 0; rb < 2; rb++)
    #pragma unroll
    for (int db = 0; db < 4; db++)
    #pragma unroll
    for (int r = 0; r < 4; r++) {
        int qg = q0 + rb*16 + lk*4 + r;
        int d = db*16 + lr;
        float v = acc[rb][db][r] / lsum[rb][r];
        ctx[((size_t)(b_idx*SEQ + qg))*HID + h*HEAD + d] = (__bf16)v;
    }
}

// ---------------- launch ----------------
extern "C" void kernel_launch(void* const* d_in, const int* in_sizes, int n_in,
                              void* d_out, int out_size, void* d_ws, size_t ws_size,
                              hipStream_t stream) {
    const float* x  = (const float*)d_in[0];   // [2,2048,768]
    const float* w1 = (const float*)d_in[1];   // [768,2304]
    const float* b1 = (const float*)d_in[2];   // [2304]
    const float* w2 = (const float*)d_in[3];   // [768,768]
    const float* b2 = (const float*)d_in[4];   // [768]
    float* out = (float*)d_out;

    char* ws = (char*)d_ws;
    size_t o = 0;
    __bf16* Xb  = (__bf16*)(ws + o); o += (size_t)MROWS*HID*2;        // 6291456
    __bf16* W1t = (__bf16*)(ws + o); o += (size_t)3*HID*HID*2;        // 3538944
    __bf16* W2t = (__bf16*)(ws + o); o += (size_t)HID*HID*2;          // 1179648
    __bf16* Qb  = (__bf16*)(ws + o); o += (size_t)MROWS*HID*2;
    __bf16* Kb  = (__bf16*)(ws + o); o += (size_t)MROWS*HID*2;
    __bf16* Vt  = (__bf16*)(ws + o); o += (size_t)MROWS*HID*2;
    __bf16* CTX = (__bf16*)(ws + o); o += (size_t)MROWS*HID*2;

    cast_f32_bf16<<<(MROWS*HID/8 + 255)/256, 256, 0, stream>>>(x, Xb, MROWS*HID/8);
    transpose_cast<<<dim3(3*HID/32, HID/32), dim3(32, 8), 0, stream>>>(w1, W1t, HID, 3*HID);
    transpose_cast<<<dim3(HID/32,   HID/32), dim3(32, 8), 0, stream>>>(w2, W2t, HID, HID);

    gemm_bt<1><<<dim3(3*HID/128, MROWS/128), 256, 0, stream>>>(
        Xb, W1t, b1, nullptr, Qb, Kb, Vt, MROWS, 3*HID, HID);

    flash_attn<<<dim3(SEQ/128, BATCH*N_HEAD), 256, 0, stream>>>(Qb, Kb, Vt, CTX);

    gemm_bt<0><<<dim3(HID/128, MROWS/128), 256, 0, stream>>>(
        CTX, W2t, b2, out, nullptr, nullptr, nullptr, MROWS, HID, HID);
}

// Round 3
// 229.543 us; speedup vs baseline: 1.2783x; 1.2783x over previous
//
#include <hip/hip_runtime.h>

typedef __bf16 bf16x8 __attribute__((ext_vector_type(8)));
typedef __bf16 bf16x4 __attribute__((ext_vector_type(4)));
typedef float  f32x4  __attribute__((ext_vector_type(4)));
typedef short  short4v __attribute__((ext_vector_type(4)));

#define N_HEAD 12
#define HEAD   64
#define HID    768
#define SEQ    2048
#define BATCH  2
#define BH     (BATCH*N_HEAD)   // 24
#define MROWS  (BATCH*SEQ)      // 4096

static __device__ __forceinline__ f32x4 mfma32(bf16x8 a, bf16x8 b, f32x4 c) {
    return __builtin_amdgcn_mfma_f32_16x16x32_bf16(a, b, c, 0, 0, 0);
}

// 16x16x16 bf16 MFMA (K=16, 4 bf16/lane) with robust builtin dispatch
static __device__ __forceinline__ f32x4 mfma_pv(bf16x4 a, bf16x4 b, f32x4 c) {
#if __has_builtin(__builtin_amdgcn_mfma_f32_16x16x16_bf16)
    return __builtin_amdgcn_mfma_f32_16x16x16_bf16(a, b, c, 0, 0, 0);
#elif __has_builtin(__builtin_amdgcn_mfma_f32_16x16x16bf16_1k)
    return __builtin_amdgcn_mfma_f32_16x16x16bf16_1k(
        __builtin_bit_cast(short4v, a), __builtin_bit_cast(short4v, b), c, 0, 0, 0);
#else
    f32x4 d;
    asm("s_nop 1\n\tv_mfma_f32_16x16x16_bf16 %0, %1, %2, %3\n\ts_nop 1"
        : "=v"(d) : "v"(a), "v"(b), "v"(c));
    return d;
#endif
}

#define GLOAD_LDS16(gp, lp) __builtin_amdgcn_global_load_lds( \
    (const __attribute__((address_space(1))) void*)(gp), \
    (__attribute__((address_space(3))) void*)(lp), 16, 0, 0)

// ---------------- cast x (fp32 -> bf16), 8 elems/thread ----------------
__global__ __launch_bounds__(256) void cast_f32_bf16(const float* __restrict__ in,
                                                     __bf16* __restrict__ out, int n8) {
    int i = blockIdx.x * 256 + threadIdx.x;
    if (i >= n8) return;
    const float4* p = (const float4*)in;
    float4 a = p[2*i], b = p[2*i+1];
    bf16x8 o;
    o[0]=(__bf16)a.x; o[1]=(__bf16)a.y; o[2]=(__bf16)a.z; o[3]=(__bf16)a.w;
    o[4]=(__bf16)b.x; o[5]=(__bf16)b.y; o[6]=(__bf16)b.z; o[7]=(__bf16)b.w;
    *(bf16x8*)&out[(size_t)8*i] = o;
}

// ------------- transpose + cast: in[R][C] fp32 -> out[C][R] bf16 -------------
__global__ __launch_bounds__(256) void transpose_cast(const float* __restrict__ in,
                                                      __bf16* __restrict__ out, int R, int C) {
    __shared__ float t[32][33];
    int bx = blockIdx.x * 32;
    int by = blockIdx.y * 32;
    int x = threadIdx.x, y = threadIdx.y;  // (32, 8)
    #pragma unroll
    for (int i = 0; i < 32; i += 8) t[y+i][x] = in[(size_t)(by+y+i)*C + bx + x];
    __syncthreads();
    #pragma unroll
    for (int i = 0; i < 32; i += 8) out[(size_t)(bx+y+i)*R + by + x] = (__bf16)t[x][y+i];
}

// ---------------- MFMA GEMM, A[M][K] bf16, Bt[N][K] bf16 ----------------
// BK=64, global_load_lds(16B) into linear LDS, both-sides XOR swizzle.
template<int EPI>
__global__ __launch_bounds__(256) void gemm_bt(
    const __bf16* __restrict__ A, const __bf16* __restrict__ Bt,
    const float* __restrict__ bias, float* __restrict__ Cout,
    __bf16* __restrict__ Qo, __bf16* __restrict__ Ko, __bf16* __restrict__ Vo,
    int M, int N, int K)
{
    __shared__ __align__(16) __bf16 As[128*64];   // 16 KiB, rows of 128 B
    __shared__ __align__(16) __bf16 Bs[128*64];
    int tid = threadIdx.x;
    int m0 = blockIdx.y * 128, n0 = blockIdx.x * 128;
    int wave = tid >> 6, lane = tid & 63, lr = lane & 15, lk = lane >> 4;
    int wr = wave >> 1, wc = wave & 1;

    f32x4 acc[4][4];
    f32x4 zz = {0.f, 0.f, 0.f, 0.f};
    #pragma unroll
    for (int m = 0; m < 4; m++)
        #pragma unroll
        for (int n = 0; n < 4; n++) acc[m][n] = zz;

    for (int k0 = 0; k0 < K; k0 += 64) {
        // stage 128x64 of A and Bt: 1024 16B-units each, 4/thread.
        // LDS unit u holds global chunk (row=u>>3, c=(u&7)^(row&7))  [involution]
        #pragma unroll
        for (int i = 0; i < 4; i++) {
            int u = tid + 256*i;
            int row = u >> 3;
            int c = (u & 7) ^ (row & 7);
            GLOAD_LDS16(&A [(size_t)(m0+row)*K + k0 + c*8], &As[(size_t)u*8]);
            GLOAD_LDS16(&Bt[(size_t)(n0+row)*K + k0 + c*8], &Bs[(size_t)u*8]);
        }
        __syncthreads();
        #pragma unroll
        for (int kk = 0; kk < 2; kk++) {
            bf16x8 af[4], bfr[4];
            #pragma unroll
            for (int m = 0; m < 4; m++) {
                int row = wr*64 + m*16 + lr;
                int byte = (row*128 + kk*64 + lk*16) ^ ((row & 7) << 4);
                af[m] = *(const bf16x8*)((const char*)As + byte);
            }
            #pragma unroll
            for (int n = 0; n < 4; n++) {
                int row = wc*64 + n*16 + lr;
                int byte = (row*128 + kk*64 + lk*16) ^ ((row & 7) << 4);
                bfr[n] = *(const bf16x8*)((const char*)Bs + byte);
            }
            #pragma unroll
            for (int m = 0; m < 4; m++)
                #pragma unroll
                for (int n = 0; n < 4; n++)
                    acc[m][n] = mfma32(af[m], bfr[n], acc[m][n]);
        }
        __syncthreads();
    }

    #pragma unroll
    for (int m = 0; m < 4; m++)
    #pragma unroll
    for (int n = 0; n < 4; n++)
    #pragma unroll
    for (int r = 0; r < 4; r++) {
        int row = m0 + wr*64 + m*16 + lk*4 + r;
        int col = n0 + wc*64 + n*16 + lr;
        float v = acc[m][n][r] + bias[col];
        if (EPI == 0) {
            Cout[(size_t)row * N + col] = v;
        } else {
            int b_idx = row >> 11, s = row & 2047;
            int which = col / HID, hc = col % HID;
            int bh = b_idx * N_HEAD + (hc >> 6);
            int d = hc & 63;
            __bf16 bv = (__bf16)v;
            if (which == 0)      Qo[((size_t)bh*SEQ + s)*HEAD + d] = bv;
            else if (which == 1) Ko[((size_t)bh*SEQ + s)*HEAD + d] = bv;
            else                 Vo[((size_t)bh*HEAD + d)*SEQ + s] = bv;
        }
    }
}

// ---------------- causal flash attention ----------------
// 1 wave per 32 q-rows. Swapped QK^T (S^T in regs) -> in-register softmax,
// LDS-free PV via 16x16x16 mfma. grid 1536 x 64thr, longest blocks first.
__global__ __launch_bounds__(64) void flash_attn(
    const __bf16* __restrict__ Q, const __bf16* __restrict__ Km,
    const __bf16* __restrict__ Vt, __bf16* __restrict__ ctx)
{
    const float SC2 = 0.125f * 1.44269504089f;  // scale * log2(e)
    int lane = threadIdx.x;
    int lr = lane & 15, lk = lane >> 4;
    int gid = blockIdx.x;
    int bh = gid % BH;
    int qi = 63 - gid / BH;          // longest (most KV tiles) first
    int b_idx = bh / N_HEAD, h = bh % N_HEAD;
    int q0 = qi * 32;
    const size_t hb = (size_t)bh * SEQ * HEAD;
    const size_t vb = (size_t)bh * HEAD * SEQ;

    bf16x8 qf[2][2];
    #pragma unroll
    for (int rb = 0; rb < 2; rb++)
        #pragma unroll
        for (int kb = 0; kb < 2; kb++)
            qf[rb][kb] = *(const bf16x8*)&Q[hb + (size_t)(q0 + rb*16 + lr)*HEAD + kb*32 + lk*8];

    f32x4 acc[2][4];
    float mst[2], lsum[2];
    f32x4 zz = {0.f, 0.f, 0.f, 0.f};
    #pragma unroll
    for (int rb = 0; rb < 2; rb++) {
        mst[rb] = -1e30f; lsum[rb] = 0.f;
        #pragma unroll
        for (int db = 0; db < 4; db++) acc[rb][db] = zz;
    }

    int nt = ((q0 + 31) >> 6) + 1;

    bf16x8 kf[4][2];
    #pragma unroll
    for (int cb = 0; cb < 4; cb++)
        #pragma unroll
        for (int kb = 0; kb < 2; kb++)
            kf[cb][kb] = *(const bf16x8*)&Km[hb + (size_t)(cb*16 + lr)*HEAD + kb*32 + lk*8];

    for (int t = 0; t < nt; t++) {
        int kv0 = t * 64;

        // V fragments for this tile (issued early; consumed by PV)
        bf16x4 vf[4][4];  // [db][cb]: V[k=kv0+cb*16+lk*4+j][d=db*16+lr]
        #pragma unroll
        for (int db = 0; db < 4; db++)
            #pragma unroll
            for (int cb = 0; cb < 4; cb++)
                vf[db][cb] = *(const bf16x4*)&Vt[vb + (size_t)(db*16 + lr)*SEQ + kv0 + cb*16 + lk*4];

        // swapped QK^T: sc[rb][cb][r] = S[q0+rb*16+lr][kv0+cb*16+lk*4+r]
        f32x4 sc[2][4];
        #pragma unroll
        for (int rb = 0; rb < 2; rb++)
            #pragma unroll
            for (int cb = 0; cb < 4; cb++) {
                f32x4 z = zz;
                z = mfma32(kf[cb][0], qf[rb][0], z);
                sc[rb][cb] = mfma32(kf[cb][1], qf[rb][1], z);
            }

        // prefetch next K tile (overlaps softmax+PV)
        if (t + 1 < nt) {
            int kv1 = kv0 + 64;
            #pragma unroll
            for (int cb = 0; cb < 4; cb++)
                #pragma unroll
                for (int kb = 0; kb < 2; kb++)
                    kf[cb][kb] = *(const bf16x8*)&Km[hb + (size_t)(kv1 + cb*16 + lr)*HEAD + kb*32 + lk*8];
        }

        // scale (+ causal mask only on diagonal-touching tiles)
        bool edge = (kv0 + 63 > q0);
        #pragma unroll
        for (int rb = 0; rb < 2; rb++)
            #pragma unroll
            for (int cb = 0; cb < 4; cb++)
                #pragma unroll
                for (int r = 0; r < 4; r++) {
                    float v = sc[rb][cb][r] * SC2;
                    if (edge) {
                        int kg = kv0 + cb*16 + lk*4 + r;
                        int qg = q0 + rb*16 + lr;
                        v = (kg <= qg) ? v : -1e30f;
                    }
                    sc[rb][cb][r] = v;
                }

        #pragma unroll
        for (int rb = 0; rb < 2; rb++) {
            // row max: 16 in-thread values + 2 cross-group shuffles
            float pm = sc[rb][0][0];
            #pragma unroll
            for (int cb = 0; cb < 4; cb++)
                #pragma unroll
                for (int r = 0; r < 4; r++) pm = fmaxf(pm, sc[rb][cb][r]);
            pm = fmaxf(pm, __shfl_xor(pm, 16));
            pm = fmaxf(pm, __shfl_xor(pm, 32));
            float mn = fmaxf(mst[rb], pm);
            float al = exp2f(mst[rb] - mn);
            mst[rb] = mn;

            bf16x4 pa[4];
            float rs = 0.f;
            #pragma unroll
            for (int cb = 0; cb < 4; cb++)
                #pragma unroll
                for (int r = 0; r < 4; r++) {
                    float p = exp2f(sc[rb][cb][r] - mn);
                    rs += p;
                    pa[cb][r] = (__bf16)p;
                }
            rs += __shfl_xor(rs, 16);
            rs += __shfl_xor(rs, 32);
            lsum[rb] = lsum[rb] * al + rs;

            // broadcast al from softmax layout (q=lr) to acc layout (q=lk*4+r)
            float alq[4];
            #pragma unroll
            for (int r = 0; r < 4; r++)
                alq[r] = __shfl(al, (lane & 48) | (lk*4 + r));
            #pragma unroll
            for (int db = 0; db < 4; db++)
                #pragma unroll
                for (int r = 0; r < 4; r++) acc[rb][db][r] *= alq[r];

            __builtin_amdgcn_s_setprio(1);
            #pragma unroll
            for (int db = 0; db < 4; db++)
                #pragma unroll
                for (int cb = 0; cb < 4; cb++)
                    acc[rb][db] = mfma_pv(pa[cb], vf[db][cb], acc[rb][db]);
            __builtin_amdgcn_s_setprio(0);
        }
    }

    #pragma unroll
    for (int rb = 0; rb < 2; rb++) {
        float rl = 1.0f / lsum[rb];
        float li[4];
        #pragma unroll
        for (int r = 0; r < 4; r++)
            li[r] = __shfl(rl, (lane & 48) | (lk*4 + r));
        #pragma unroll
        for (int db = 0; db < 4; db++)
            #pragma unroll
            for (int r = 0; r < 4; r++) {
                int qg = q0 + rb*16 + lk*4 + r;
                int d = db*16 + lr;
                ctx[((size_t)(b_idx*SEQ + qg))*HID + h*HEAD + d] = (__bf16)(acc[rb][db][r] * li[r]);
            }
    }
}

// ---------------- launch ----------------
extern "C" void kernel_launch(void* const* d_in, const int* in_sizes, int n_in,
                              void* d_out, int out_size, void* d_ws, size_t ws_size,
                              hipStream_t stream) {
    const float* x  = (const float*)d_in[0];   // [2,2048,768]
    const float* w1 = (const float*)d_in[1];   // [768,2304]
    const float* b1 = (const float*)d_in[2];   // [2304]
    const float* w2 = (const float*)d_in[3];   // [768,768]
    const float* b2 = (const float*)d_in[4];   // [768]
    float* out = (float*)d_out;

    char* ws = (char*)d_ws;
    size_t o = 0;
    __bf16* Xb  = (__bf16*)(ws + o); o += (size_t)MROWS*HID*2;
    __bf16* W1t = (__bf16*)(ws + o); o += (size_t)3*HID*HID*2;
    __bf16* W2t = (__bf16*)(ws + o); o += (size_t)HID*HID*2;
    __bf16* Qb  = (__bf16*)(ws + o); o += (size_t)MROWS*HID*2;
    __bf16* Kb  = (__bf16*)(ws + o); o += (size_t)MROWS*HID*2;
    __bf16* Vt  = (__bf16*)(ws + o); o += (size_t)MROWS*HID*2;
    __bf16* CTX = (__bf16*)(ws + o); o += (size_t)MROWS*HID*2;

    cast_f32_bf16<<<(MROWS*HID/8 + 255)/256, 256, 0, stream>>>(x, Xb, MROWS*HID/8);
    transpose_cast<<<dim3(3*HID/32, HID/32), dim3(32, 8), 0, stream>>>(w1, W1t, HID, 3*HID);
    transpose_cast<<<dim3(HID/32,   HID/32), dim3(32, 8), 0, stream>>>(w2, W2t, HID, HID);

    gemm_bt<1><<<dim3(3*HID/128, MROWS/128), 256, 0, stream>>>(
        Xb, W1t, b1, nullptr, Qb, Kb, Vt, MROWS, 3*HID, HID);

    flash_attn<<<dim3(64*BH), 64, 0, stream>>>(Qb, Kb, Vt, CTX);

    gemm_bt<0><<<dim3(HID/128, MROWS/128), 256, 0, stream>>>(
        CTX, W2t, b2, out, nullptr, nullptr, nullptr, MROWS, HID, HID);
}